// Round 2
// baseline (1281.365 us; speedup 1.0000x reference)
//
#include <hip/hip_runtime.h>
#include <hip/hip_bf16.h>
#include <math.h>

#define B 32
#define S 4096
#define H 16
#define QC 1536
#define LORA 512
#define ROPE 64
#define NOPE 128
#define VH 128
#define DM 2048
#define NC 32          // chunks per batch for flash split-K
#define CHUNK (S / NC) // 128 rows per chunk
#define RT 8           // rows per fully-unrolled tile

__device__ __constant__ float SCALE_C = 0.07216878364870323f; // 1/sqrt(192)

// ---------------- Kernel 1: q_t = q_c @ W_UQ  (32x2048), qr = q_c @ W_QR (32x1024)
__global__ void k_proj1(const float* __restrict__ q_c, const float* __restrict__ W_UQ,
                        const float* __restrict__ W_QR, float* __restrict__ q_t,
                        float* __restrict__ qr) {
    __shared__ float qs[QC];
    const int b = blockIdx.y, sl = blockIdx.x, t = threadIdx.x;
    for (int i = t; i < QC / 4; i += 256)
        ((float4*)qs)[i] = ((const float4*)(q_c + (size_t)b * QC))[i];
    __syncthreads();

    const float* W;
    float* out;
    int col0, N;
    if (sl < 8) { W = W_UQ; out = q_t + (size_t)b * 2048; col0 = sl * 256; N = 2048; }
    else        { W = W_QR; out = qr  + (size_t)b * 1024; col0 = (sl - 8) * 256; N = 1024; }
    const int col = col0 + t;
    float acc = 0.f;
    for (int d = 0; d < QC; d += 4) {
        float4 q4 = *(const float4*)(qs + d);
        acc += q4.x * W[(size_t)d * N + col];
        acc += q4.y * W[(size_t)(d + 1) * N + col];
        acc += q4.z * W[(size_t)(d + 2) * N + col];
        acc += q4.w * W[(size_t)(d + 3) * N + col];
    }
    out[col] = acc;
}

// ---------------- Kernel 2: RoPE  (q_pe from qr; kpe_rot from k_pe)
__global__ void k_rope(const float* __restrict__ qr, const float* __restrict__ k_pe,
                       const int* __restrict__ pos_arr, float* __restrict__ q_pe,
                       float* __restrict__ kpe_rot) {
    const int b = blockIdx.x, t = threadIdx.x;
    const int pos = pos_arr[b];
    for (int p = t; p < (H + 1) * 32; p += 256) {
        const int j = p & 31;       // freq index 0..31
        const int grp = p >> 5;     // 0..15 heads, 16 = k_pe
        const double inv = pow(10000.0, -(double)j / 32.0);
        const double f = (double)pos * inv;
        const float c = (float)cos(f), s = (float)sin(f);
        if (grp < H) {
            const float* x = qr + (size_t)b * 1024 + grp * 64;
            float* o = q_pe + (size_t)b * 1024 + grp * 64;
            const float x1 = x[j], x2 = x[j + 32];
            o[j] = x1 * c - x2 * s;
            o[j + 32] = x2 * c + x1 * s;
        } else {
            const float* x = k_pe + (size_t)b * 64;
            float* o = kpe_rot + (size_t)b * 64;
            const float x1 = x[j], x2 = x[j + 32];
            o[j] = x1 * c - x2 * s;
            o[j + 32] = x2 * c + x1 * s;
        }
    }
}

// ---------------- Kernel 3: q_nope[b,h,l] = sum_n q_t[b,h,n] * W_UK[l,h,n]
__global__ void k_qnope(const float* __restrict__ q_t, const float* __restrict__ W_UK,
                        float* __restrict__ q_nope) {
    const int h = blockIdx.x, b = blockIdx.y, t = threadIdx.x;
    __shared__ float qs[NOPE];
    if (t < NOPE) qs[t] = q_t[(size_t)b * 2048 + h * NOPE + t];
    __syncthreads();
    for (int l = t; l < LORA; l += 256) {
        const float* w = W_UK + (size_t)l * (H * NOPE) + h * NOPE;
        float acc = 0.f;
        for (int n = 0; n < NOPE; n += 4) {
            float4 w4 = *(const float4*)(w + n);
            float4 q4 = *(const float4*)(qs + n);
            acc += q4.x * w4.x + q4.y * w4.y + q4.z * w4.z + q4.w * w4.w;
        }
        q_nope[((size_t)b * H + h) * LORA + l] = acc;
    }
}

// ---------------- Kernel 4: flash decode over chunks -> partial (m, l, o)
// Block = 256 threads = 16 groups of 16 lanes; group g owns head g.
// Thread (g,j) holds q elements {4j..4j+3} + 64k (k=0..8; k=8 is the RoPE part)
// K-loop processes RT=8 rows per tile, FULLY unrolled so sc[] stays in VGPRs.
__global__ __launch_bounds__(256, 4) void k_flash(
    const float* __restrict__ q_nope, const float* __restrict__ q_pe,
    const float* __restrict__ kv_cache, const float* __restrict__ kpe_cache,
    const float* __restrict__ k_c_normed, const float* __restrict__ kpe_rot,
    const int* __restrict__ pos_arr, float* __restrict__ part_o,
    float* __restrict__ part_ml) {
    const int blk = blockIdx.x;
    const int b = blk / NC, c = blk % NC;
    const int t = threadIdx.x;
    const int g = t >> 4, j = t & 15;
    const int pos = pos_arr[b];

    const float* kv_b = kv_cache + (size_t)b * S * LORA;
    const float* kp_b = kpe_cache + (size_t)b * S * ROPE;
    const float* kc_b = k_c_normed + (size_t)b * LORA;
    const float* kr_b = kpe_rot + (size_t)b * ROPE;

    float4 q4[9];
    const float* qn = q_nope + ((size_t)b * H + g) * LORA;
#pragma unroll
    for (int k = 0; k < 8; k++) q4[k] = *(const float4*)(qn + 4 * j + 64 * k);
    q4[8] = *(const float4*)(q_pe + ((size_t)b * H + g) * 64 + 4 * j);

    float m_run = -INFINITY, l_run = 0.f;
    float4 o_acc[8];
#pragma unroll
    for (int k = 0; k < 8; k++) o_acc[k] = make_float4(0.f, 0.f, 0.f, 0.f);

    const int s0 = c * CHUNK;
    for (int st = 0; st < CHUNK; st += RT) {
        float sc[RT];
#pragma unroll
        for (int r = 0; r < RT; r++) {
            const int s = s0 + st + r;
            const float* kvr = (s == pos) ? kc_b : (kv_b + (size_t)s * LORA);
            const float* per = (s == pos) ? kr_b : (kp_b + (size_t)s * ROPE);
            float acc = 0.f;
#pragma unroll
            for (int k = 0; k < 8; k++) {
                float4 kv4 = *(const float4*)(kvr + 4 * j + 64 * k);
                acc += q4[k].x * kv4.x + q4[k].y * kv4.y + q4[k].z * kv4.z + q4[k].w * kv4.w;
            }
            float4 p4 = *(const float4*)(per + 4 * j);
            acc += q4[8].x * p4.x + q4[8].y * p4.y + q4[8].z * p4.z + q4[8].w * p4.w;
            // reduce over the 16 lanes of this group
            acc += __shfl_xor(acc, 8);
            acc += __shfl_xor(acc, 4);
            acc += __shfl_xor(acc, 2);
            acc += __shfl_xor(acc, 1);
            sc[r] = acc * SCALE_C;
        }
        float mt = sc[0];
#pragma unroll
        for (int r = 1; r < RT; r++) mt = fmaxf(mt, sc[r]);
        const float m_new = fmaxf(m_run, mt);
        const float alpha = __expf(m_run - m_new);
        float psum = 0.f;
#pragma unroll
        for (int r = 0; r < RT; r++) { sc[r] = __expf(sc[r] - m_new); psum += sc[r]; }
        l_run = l_run * alpha + psum;
        m_run = m_new;
#pragma unroll
        for (int k = 0; k < 8; k++) {
            o_acc[k].x *= alpha; o_acc[k].y *= alpha;
            o_acc[k].z *= alpha; o_acc[k].w *= alpha;
        }
#pragma unroll
        for (int r = 0; r < RT; r++) {
            const int s = s0 + st + r;
            const float* kvr = (s == pos) ? kc_b : (kv_b + (size_t)s * LORA);
            const float p = sc[r];
#pragma unroll
            for (int k = 0; k < 8; k++) {
                float4 kv4 = *(const float4*)(kvr + 4 * j + 64 * k);
                o_acc[k].x += p * kv4.x; o_acc[k].y += p * kv4.y;
                o_acc[k].z += p * kv4.z; o_acc[k].w += p * kv4.w;
            }
        }
    }
    float* po = part_o + (((size_t)b * NC + c) * H + g) * LORA;
#pragma unroll
    for (int k = 0; k < 8; k++) *(float4*)(po + 4 * j + 64 * k) = o_acc[k];
    if (j == 0) {
        float* pml = part_ml + (((size_t)b * NC + c) * H + g) * 2;
        pml[0] = m_run;
        pml[1] = l_run;
    }
}

// ---------------- Kernel 5: combine partials -> o (in LDS), fused v = o . W_UV
__global__ void k_combine(const float* __restrict__ part_o, const float* __restrict__ part_ml,
                          const float* __restrict__ W_UV, float* __restrict__ v) {
    const int h = blockIdx.x, b = blockIdx.y, t = threadIdx.x; // 128 threads
    __shared__ float o_s[LORA];
    float m = -INFINITY;
    for (int c = 0; c < NC; c++)
        m = fmaxf(m, part_ml[(((size_t)b * NC + c) * H + h) * 2]);
    float l = 0.f;
    for (int c = 0; c < NC; c++) {
        const float* pml = part_ml + (((size_t)b * NC + c) * H + h) * 2;
        l += pml[1] * __expf(pml[0] - m);
    }
    const float inv_l = 1.0f / l;
    for (int li = t; li < LORA; li += 128) {
        float acc = 0.f;
        for (int c = 0; c < NC; c++) {
            const float scf = __expf(part_ml[(((size_t)b * NC + c) * H + h) * 2] - m);
            acc += part_o[(((size_t)b * NC + c) * H + h) * LORA + li] * scf;
        }
        o_s[li] = acc * inv_l;
    }
    __syncthreads();
    // v[b, h*128 + t] = sum_l o_s[l] * W_UV[l, h, t]
    float acc = 0.f;
    for (int l2 = 0; l2 < LORA; l2++)
        acc += o_s[l2] * W_UV[(size_t)l2 * (H * VH) + h * VH + t];
    v[(size_t)b * (H * VH) + h * VH + t] = acc;
}

// ---------------- Kernel 6: out_part[ks] = V[:, k-slice] @ W_O[k-slice, :]
__global__ void k_out(const float* __restrict__ v, const float* __restrict__ W_O,
                      float* __restrict__ out_part) {
    const int dsl = blockIdx.x, ksl = blockIdx.y, t = threadIdx.x;
    const int d0 = dsl * 128, k0 = ksl * 128;
    __shared__ float vs[32][128];
    for (int i = t; i < 32 * 128; i += 256) {
        const int bi = i >> 7, kk = i & 127;
        vs[bi][kk] = v[(size_t)bi * DM + k0 + kk];
    }
    __syncthreads();
    const int dl = t & 127, bh = t >> 7; // bh = 0/1 -> batches 0..15 / 16..31
    float acc[16];
#pragma unroll
    for (int i = 0; i < 16; i++) acc[i] = 0.f;
    for (int kk = 0; kk < 128; kk++) {
        const float w = W_O[(size_t)(k0 + kk) * DM + d0 + dl];
#pragma unroll
        for (int i = 0; i < 16; i++) acc[i] += vs[bh * 16 + i][kk] * w;
    }
    float* op = out_part + (size_t)ksl * 32 * DM;
#pragma unroll
    for (int i = 0; i < 16; i++) op[(size_t)(bh * 16 + i) * DM + d0 + dl] = acc[i];
}

// ---------------- Kernel 7: reduce the 16 split-K partials
__global__ void k_out_reduce(const float* __restrict__ out_part, float* __restrict__ out) {
    const int idx = blockIdx.x * 256 + threadIdx.x; // 16384 threads * 4 elems
    float4 acc = make_float4(0.f, 0.f, 0.f, 0.f);
    for (int ks = 0; ks < 16; ks++) {
        float4 p = *(const float4*)(out_part + (size_t)ks * (32 * DM) + (size_t)idx * 4);
        acc.x += p.x; acc.y += p.y; acc.z += p.z; acc.w += p.w;
    }
    *(float4*)(out + (size_t)idx * 4) = acc;
}

extern "C" void kernel_launch(void* const* d_in, const int* in_sizes, int n_in,
                              void* d_out, int out_size, void* d_ws, size_t ws_size,
                              hipStream_t stream) {
    const float* q_c        = (const float*)d_in[0];
    const float* k_c_normed = (const float*)d_in[1];
    const float* k_pe       = (const float*)d_in[2];
    const float* kv_c_cache = (const float*)d_in[3];
    const float* k_pe_cache = (const float*)d_in[4];
    const float* W_UQ       = (const float*)d_in[5];
    const float* W_UK       = (const float*)d_in[6];
    const float* W_QR       = (const float*)d_in[7];
    const float* W_UV       = (const float*)d_in[8];
    const float* W_O        = (const float*)d_in[9];
    const int*   pos        = (const int*)d_in[10];

    float* ws = (float*)d_ws;
    float* q_t      = ws;                       // 65536
    float* qr       = q_t + 65536;              // 32768
    float* q_pe     = qr + 32768;               // 32768
    float* kpe_rot  = q_pe + 32768;             // 2048
    float* q_nope   = kpe_rot + 2048;           // 262144
    float* part_o   = q_nope + 262144;          // 32*NC*16*512 = 8388608
    float* part_ml  = part_o + (size_t)B * NC * H * LORA;   // 32768
    float* v        = part_ml + (size_t)B * NC * H * 2;     // 65536
    float* out_part = v + 65536;                // 16*32*2048 = 1048576

    k_proj1<<<dim3(12, 32), 256, 0, stream>>>(q_c, W_UQ, W_QR, q_t, qr);
    k_rope<<<32, 256, 0, stream>>>(qr, k_pe, pos, q_pe, kpe_rot);
    k_qnope<<<dim3(16, 32), 256, 0, stream>>>(q_t, W_UK, q_nope);
    k_flash<<<B * NC, 256, 0, stream>>>(q_nope, q_pe, kv_c_cache, k_pe_cache,
                                        k_c_normed, kpe_rot, pos, part_o, part_ml);
    k_combine<<<dim3(16, 32), 128, 0, stream>>>(part_o, part_ml, W_UV, v);
    k_out<<<dim3(16, 16), 256, 0, stream>>>(v, W_O, out_part);
    k_out_reduce<<<64, 256, 0, stream>>>(out_part, (float*)d_out);
}

// Round 3
// 381.776 us; speedup vs baseline: 3.3563x; 3.3563x over previous
//
#include <hip/hip_runtime.h>
#include <hip/hip_bf16.h>
#include <math.h>

#define B 32
#define S 4096
#define H 16
#define QC 1536
#define LORA 512
#define ROPE 64
#define NOPE 128
#define VH 128
#define DM 2048
#define NC 32          // chunks per batch for flash split-K
#define CHUNK (S / NC) // 128 rows per chunk

__device__ __constant__ float SCALE_C = 0.07216878364870323f; // 1/sqrt(192)

// ---------------- Kernel 1: q_t = q_c @ W_UQ  (32x2048), qr = q_c @ W_QR (32x1024)
__global__ void k_proj1(const float* __restrict__ q_c, const float* __restrict__ W_UQ,
                        const float* __restrict__ W_QR, float* __restrict__ q_t,
                        float* __restrict__ qr) {
    __shared__ float qs[QC];
    const int b = blockIdx.y, sl = blockIdx.x, t = threadIdx.x;
    for (int i = t; i < QC / 4; i += 256)
        ((float4*)qs)[i] = ((const float4*)(q_c + (size_t)b * QC))[i];
    __syncthreads();

    const float* W;
    float* out;
    int col0, N;
    if (sl < 8) { W = W_UQ; out = q_t + (size_t)b * 2048; col0 = sl * 256; N = 2048; }
    else        { W = W_QR; out = qr  + (size_t)b * 1024; col0 = (sl - 8) * 256; N = 1024; }
    const int col = col0 + t;
    float acc = 0.f;
    for (int d = 0; d < QC; d += 4) {
        float4 q4 = *(const float4*)(qs + d);
        acc += q4.x * W[(size_t)d * N + col];
        acc += q4.y * W[(size_t)(d + 1) * N + col];
        acc += q4.z * W[(size_t)(d + 2) * N + col];
        acc += q4.w * W[(size_t)(d + 3) * N + col];
    }
    out[col] = acc;
}

// ---------------- Kernel 2: RoPE  (q_pe from qr; kpe_rot from k_pe)
__global__ void k_rope(const float* __restrict__ qr, const float* __restrict__ k_pe,
                       const int* __restrict__ pos_arr, float* __restrict__ q_pe,
                       float* __restrict__ kpe_rot) {
    const int b = blockIdx.x, t = threadIdx.x;
    const int pos = pos_arr[b];
    for (int p = t; p < (H + 1) * 32; p += 256) {
        const int j = p & 31;       // freq index 0..31
        const int grp = p >> 5;     // 0..15 heads, 16 = k_pe
        const double inv = pow(10000.0, -(double)j / 32.0);
        const double f = (double)pos * inv;
        const float c = (float)cos(f), s = (float)sin(f);
        if (grp < H) {
            const float* x = qr + (size_t)b * 1024 + grp * 64;
            float* o = q_pe + (size_t)b * 1024 + grp * 64;
            const float x1 = x[j], x2 = x[j + 32];
            o[j] = x1 * c - x2 * s;
            o[j + 32] = x2 * c + x1 * s;
        } else {
            const float* x = k_pe + (size_t)b * 64;
            float* o = kpe_rot + (size_t)b * 64;
            const float x1 = x[j], x2 = x[j + 32];
            o[j] = x1 * c - x2 * s;
            o[j + 32] = x2 * c + x1 * s;
        }
    }
}

// ---------------- Kernel 3: q_nope[b,h,l] = sum_n q_t[b,h,n] * W_UK[l,h,n]
__global__ void k_qnope(const float* __restrict__ q_t, const float* __restrict__ W_UK,
                        float* __restrict__ q_nope) {
    const int h = blockIdx.x, b = blockIdx.y, t = threadIdx.x;
    __shared__ float qs[NOPE];
    if (t < NOPE) qs[t] = q_t[(size_t)b * 2048 + h * NOPE + t];
    __syncthreads();
    for (int l = t; l < LORA; l += 256) {
        const float* w = W_UK + (size_t)l * (H * NOPE) + h * NOPE;
        float acc = 0.f;
        for (int n = 0; n < NOPE; n += 4) {
            float4 w4 = *(const float4*)(w + n);
            float4 q4 = *(const float4*)(qs + n);
            acc += q4.x * w4.x + q4.y * w4.y + q4.z * w4.z + q4.w * w4.w;
        }
        q_nope[((size_t)b * H + h) * LORA + l] = acc;
    }
}

// ---------------- Kernel 4: fused single-pass flash decode -> partial (m, l, o)
// Block = 256 threads = 16 groups of 16 lanes; group g owns head g.
// Thread (g,j) holds q elems {4j..4j+3}+64k (k=0..8; k=8 = RoPE part).
// Per key row: load row ONCE into regs, QK dot + shfl-reduce, defer-max online
// softmax (THR=8), PV accumulate from the SAME registers. No sc[] array.
__global__ __launch_bounds__(256) void k_flash(
    const float* __restrict__ q_nope, const float* __restrict__ q_pe,
    const float* __restrict__ kv_cache, const float* __restrict__ kpe_cache,
    const float* __restrict__ k_c_normed, const float* __restrict__ kpe_rot,
    const int* __restrict__ pos_arr, float* __restrict__ part_o,
    float* __restrict__ part_ml) {
    const int blk = blockIdx.x;
    const int b = blk / NC, c = blk % NC;
    const int t = threadIdx.x;
    const int g = t >> 4, j = t & 15;
    const int pos = pos_arr[b];

    const float* kv_b = kv_cache + (size_t)b * S * LORA;
    const float* kp_b = kpe_cache + (size_t)b * S * ROPE;
    const float* kc_b = k_c_normed + (size_t)b * LORA;
    const float* kr_b = kpe_rot + (size_t)b * ROPE;

    float4 q4[9];
    const float* qn = q_nope + ((size_t)b * H + g) * LORA;
#pragma unroll
    for (int k = 0; k < 8; k++) q4[k] = *(const float4*)(qn + 4 * j + 64 * k);
    q4[8] = *(const float4*)(q_pe + ((size_t)b * H + g) * 64 + 4 * j);

    float m_run = -INFINITY, l_run = 0.f;
    float4 o_acc[8];
#pragma unroll
    for (int k = 0; k < 8; k++) o_acc[k] = make_float4(0.f, 0.f, 0.f, 0.f);

    const int s0 = c * CHUNK;
    for (int r = 0; r < CHUNK; ++r) {
        const int s = s0 + r;
        const float* kvr = (s == pos) ? kc_b : (kv_b + (size_t)s * LORA);
        const float* per = (s == pos) ? kr_b : (kp_b + (size_t)s * ROPE);

        float4 kv4[8];
#pragma unroll
        for (int k = 0; k < 8; k++) kv4[k] = *(const float4*)(kvr + 4 * j + 64 * k);
        float4 p4 = *(const float4*)(per + 4 * j);

        float acc = 0.f;
#pragma unroll
        for (int k = 0; k < 8; k++)
            acc += q4[k].x * kv4[k].x + q4[k].y * kv4[k].y +
                   q4[k].z * kv4[k].z + q4[k].w * kv4[k].w;
        acc += q4[8].x * p4.x + q4[8].y * p4.y + q4[8].z * p4.z + q4[8].w * p4.w;
        // reduce over the 16 lanes of this group (all lanes get the sum)
        acc += __shfl_xor(acc, 8);
        acc += __shfl_xor(acc, 4);
        acc += __shfl_xor(acc, 2);
        acc += __shfl_xor(acc, 1);
        const float sc = acc * SCALE_C;

        if (sc > m_run + 8.0f) {  // defer-max: rescale only on big max growth
            const float alpha = __expf(m_run - sc); // exp(-inf)=0 on first hit
            l_run *= alpha;
#pragma unroll
            for (int k = 0; k < 8; k++) {
                o_acc[k].x *= alpha; o_acc[k].y *= alpha;
                o_acc[k].z *= alpha; o_acc[k].w *= alpha;
            }
            m_run = sc;
        }
        const float p = __expf(sc - m_run);  // bounded by e^8
        l_run += p;
#pragma unroll
        for (int k = 0; k < 8; k++) {
            o_acc[k].x += p * kv4[k].x; o_acc[k].y += p * kv4[k].y;
            o_acc[k].z += p * kv4[k].z; o_acc[k].w += p * kv4[k].w;
        }
    }
    float* po = part_o + (((size_t)b * NC + c) * H + g) * LORA;
#pragma unroll
    for (int k = 0; k < 8; k++) *(float4*)(po + 4 * j + 64 * k) = o_acc[k];
    if (j == 0) {
        float* pml = part_ml + (((size_t)b * NC + c) * H + g) * 2;
        pml[0] = m_run;
        pml[1] = l_run;
    }
}

// ---------------- Kernel 5: combine partials -> o (in LDS), fused v = o . W_UV
__global__ void k_combine(const float* __restrict__ part_o, const float* __restrict__ part_ml,
                          const float* __restrict__ W_UV, float* __restrict__ v) {
    const int h = blockIdx.x, b = blockIdx.y, t = threadIdx.x; // 128 threads
    __shared__ float o_s[LORA];
    float m = -INFINITY;
    for (int c = 0; c < NC; c++)
        m = fmaxf(m, part_ml[(((size_t)b * NC + c) * H + h) * 2]);
    float l = 0.f;
    for (int c = 0; c < NC; c++) {
        const float* pml = part_ml + (((size_t)b * NC + c) * H + h) * 2;
        l += pml[1] * __expf(pml[0] - m);
    }
    const float inv_l = 1.0f / l;
    for (int li = t; li < LORA; li += 128) {
        float acc = 0.f;
        for (int c = 0; c < NC; c++) {
            const float scf = __expf(part_ml[(((size_t)b * NC + c) * H + h) * 2] - m);
            acc += part_o[(((size_t)b * NC + c) * H + h) * LORA + li] * scf;
        }
        o_s[li] = acc * inv_l;
    }
    __syncthreads();
    // v[b, h*128 + t] = sum_l o_s[l] * W_UV[l, h, t]
    float acc = 0.f;
    for (int l2 = 0; l2 < LORA; l2++)
        acc += o_s[l2] * W_UV[(size_t)l2 * (H * VH) + h * VH + t];
    v[(size_t)b * (H * VH) + h * VH + t] = acc;
}

// ---------------- Kernel 6: out_part[ks] = V[:, k-slice] @ W_O[k-slice, :]
__global__ void k_out(const float* __restrict__ v, const float* __restrict__ W_O,
                      float* __restrict__ out_part) {
    const int dsl = blockIdx.x, ksl = blockIdx.y, t = threadIdx.x;
    const int d0 = dsl * 128, k0 = ksl * 128;
    __shared__ float vs[32][128];
    for (int i = t; i < 32 * 128; i += 256) {
        const int bi = i >> 7, kk = i & 127;
        vs[bi][kk] = v[(size_t)bi * DM + k0 + kk];
    }
    __syncthreads();
    const int dl = t & 127, bh = t >> 7; // bh = 0/1 -> batches 0..15 / 16..31
    float acc[16];
#pragma unroll
    for (int i = 0; i < 16; i++) acc[i] = 0.f;
    for (int kk = 0; kk < 128; kk++) {
        const float w = W_O[(size_t)(k0 + kk) * DM + d0 + dl];
#pragma unroll
        for (int i = 0; i < 16; i++) acc[i] += vs[bh * 16 + i][kk] * w;
    }
    float* op = out_part + (size_t)ksl * 32 * DM;
#pragma unroll
    for (int i = 0; i < 16; i++) op[(size_t)(bh * 16 + i) * DM + d0 + dl] = acc[i];
}

// ---------------- Kernel 7: reduce the 16 split-K partials
__global__ void k_out_reduce(const float* __restrict__ out_part, float* __restrict__ out) {
    const int idx = blockIdx.x * 256 + threadIdx.x; // 16384 threads * 4 elems
    float4 acc = make_float4(0.f, 0.f, 0.f, 0.f);
    for (int ks = 0; ks < 16; ks++) {
        float4 p = *(const float4*)(out_part + (size_t)ks * (32 * DM) + (size_t)idx * 4);
        acc.x += p.x; acc.y += p.y; acc.z += p.z; acc.w += p.w;
    }
    *(float4*)(out + (size_t)idx * 4) = acc;
}

extern "C" void kernel_launch(void* const* d_in, const int* in_sizes, int n_in,
                              void* d_out, int out_size, void* d_ws, size_t ws_size,
                              hipStream_t stream) {
    const float* q_c        = (const float*)d_in[0];
    const float* k_c_normed = (const float*)d_in[1];
    const float* k_pe       = (const float*)d_in[2];
    const float* kv_c_cache = (const float*)d_in[3];
    const float* k_pe_cache = (const float*)d_in[4];
    const float* W_UQ       = (const float*)d_in[5];
    const float* W_UK       = (const float*)d_in[6];
    const float* W_QR       = (const float*)d_in[7];
    const float* W_UV       = (const float*)d_in[8];
    const float* W_O        = (const float*)d_in[9];
    const int*   pos        = (const int*)d_in[10];

    float* ws = (float*)d_ws;
    float* q_t      = ws;                       // 65536
    float* qr       = q_t + 65536;              // 32768
    float* q_pe     = qr + 32768;               // 32768
    float* kpe_rot  = q_pe + 32768;             // 2048
    float* q_nope   = kpe_rot + 2048;           // 262144
    float* part_o   = q_nope + 262144;          // 32*NC*16*512 = 8388608
    float* part_ml  = part_o + (size_t)B * NC * H * LORA;   // 32768
    float* v        = part_ml + (size_t)B * NC * H * 2;     // 65536
    float* out_part = v + 65536;                // 16*32*2048 = 1048576

    k_proj1<<<dim3(12, 32), 256, 0, stream>>>(q_c, W_UQ, W_QR, q_t, qr);
    k_rope<<<32, 256, 0, stream>>>(qr, k_pe, pos, q_pe, kpe_rot);
    k_qnope<<<dim3(16, 32), 256, 0, stream>>>(q_t, W_UK, q_nope);
    k_flash<<<B * NC, 256, 0, stream>>>(q_nope, q_pe, kv_c_cache, k_pe_cache,
                                        k_c_normed, kpe_rot, pos, part_o, part_ml);
    k_combine<<<dim3(16, 32), 128, 0, stream>>>(part_o, part_ml, W_UV, v);
    k_out<<<dim3(16, 16), 256, 0, stream>>>(v, W_O, out_part);
    k_out_reduce<<<64, 256, 0, stream>>>(out_part, (float*)d_out);
}

// Round 4
// 316.311 us; speedup vs baseline: 4.0510x; 1.2070x over previous
//
#include <hip/hip_runtime.h>
#include <hip/hip_bf16.h>
#include <math.h>

#define B 32
#define S 4096
#define H 16
#define QC 1536
#define LORA 512
#define ROPE 64
#define NOPE 128
#define VH 128
#define DM 2048
#define NC 32          // chunks per batch for flash split-K
#define CHUNK (S / NC) // 128 rows per chunk
#define TR 8           // rows per staged LDS tile
#define NT (CHUNK / TR)

__device__ __constant__ float SCALE_C = 0.07216878364870323f; // 1/sqrt(192)

// ---------------- Kernel 1: q_t = q_c @ W_UQ  (32x2048), qr = q_c @ W_QR (32x1024)
__global__ void k_proj1(const float* __restrict__ q_c, const float* __restrict__ W_UQ,
                        const float* __restrict__ W_QR, float* __restrict__ q_t,
                        float* __restrict__ qr) {
    __shared__ float qs[QC];
    const int b = blockIdx.y, sl = blockIdx.x, t = threadIdx.x;
    for (int i = t; i < QC / 4; i += 256)
        ((float4*)qs)[i] = ((const float4*)(q_c + (size_t)b * QC))[i];
    __syncthreads();

    const float* W;
    float* out;
    int col0, N;
    if (sl < 8) { W = W_UQ; out = q_t + (size_t)b * 2048; col0 = sl * 256; N = 2048; }
    else        { W = W_QR; out = qr  + (size_t)b * 1024; col0 = (sl - 8) * 256; N = 1024; }
    const int col = col0 + t;
    float acc = 0.f;
    for (int d = 0; d < QC; d += 4) {
        float4 q4 = *(const float4*)(qs + d);
        acc += q4.x * W[(size_t)d * N + col];
        acc += q4.y * W[(size_t)(d + 1) * N + col];
        acc += q4.z * W[(size_t)(d + 2) * N + col];
        acc += q4.w * W[(size_t)(d + 3) * N + col];
    }
    out[col] = acc;
}

// ---------------- Kernel 2: RoPE  (q_pe from qr; kpe_rot from k_pe)
__global__ void k_rope(const float* __restrict__ qr, const float* __restrict__ k_pe,
                       const int* __restrict__ pos_arr, float* __restrict__ q_pe,
                       float* __restrict__ kpe_rot) {
    const int b = blockIdx.x, t = threadIdx.x;
    const int pos = pos_arr[b];
    for (int p = t; p < (H + 1) * 32; p += 256) {
        const int j = p & 31;       // freq index 0..31
        const int grp = p >> 5;     // 0..15 heads, 16 = k_pe
        const double inv = pow(10000.0, -(double)j / 32.0);
        const double f = (double)pos * inv;
        const float c = (float)cos(f), s = (float)sin(f);
        if (grp < H) {
            const float* x = qr + (size_t)b * 1024 + grp * 64;
            float* o = q_pe + (size_t)b * 1024 + grp * 64;
            const float x1 = x[j], x2 = x[j + 32];
            o[j] = x1 * c - x2 * s;
            o[j + 32] = x2 * c + x1 * s;
        } else {
            const float* x = k_pe + (size_t)b * 64;
            float* o = kpe_rot + (size_t)b * 64;
            const float x1 = x[j], x2 = x[j + 32];
            o[j] = x1 * c - x2 * s;
            o[j + 32] = x2 * c + x1 * s;
        }
    }
}

// ---------------- Kernel 3: q_nope[b,h,l] = sum_n q_t[b,h,n] * W_UK[l,h,n]
__global__ void k_qnope(const float* __restrict__ q_t, const float* __restrict__ W_UK,
                        float* __restrict__ q_nope) {
    const int h = blockIdx.x, b = blockIdx.y, t = threadIdx.x;
    __shared__ float qs[NOPE];
    if (t < NOPE) qs[t] = q_t[(size_t)b * 2048 + h * NOPE + t];
    __syncthreads();
    for (int l = t; l < LORA; l += 256) {
        const float* w = W_UK + (size_t)l * (H * NOPE) + h * NOPE;
        float acc = 0.f;
        for (int n = 0; n < NOPE; n += 4) {
            float4 w4 = *(const float4*)(w + n);
            float4 q4 = *(const float4*)(qs + n);
            acc += q4.x * w4.x + q4.y * w4.y + q4.z * w4.z + q4.w * w4.w;
        }
        q_nope[((size_t)b * H + h) * LORA + l] = acc;
    }
}

// ---------------- Kernel 4: flash decode, LDS double-buffered via global_load_lds
// Block = 256 threads = 16 groups of 16 lanes; group g owns head g.
// 2-phase pipeline: stage tile t+1 into buf^1 (async direct-to-LDS) while all
// 4 waves compute tile t from buf. pos-row is patched into LDS at stage time.
__global__ __launch_bounds__(256) void k_flash(
    const float* __restrict__ q_nope, const float* __restrict__ q_pe,
    const float* __restrict__ kv_cache, const float* __restrict__ kpe_cache,
    const float* __restrict__ k_c_normed, const float* __restrict__ kpe_rot,
    const int* __restrict__ pos_arr, float* __restrict__ part_o,
    float* __restrict__ part_ml) {
    __shared__ float lds_kv[2][TR][LORA]; // 32 KB
    __shared__ float lds_pe[2][TR][ROPE]; //  4 KB
    const int blk = blockIdx.x;
    const int b = blk / NC, c = blk % NC;
    const int t = threadIdx.x;
    const int g = t >> 4, j = t & 15;
    const int wave = t >> 6, lane = t & 63;
    const int pos = pos_arr[b];
    const int s0 = c * CHUNK;
    const int rel = pos - s0;
    const int ptile = (rel >= 0 && rel < CHUNK) ? (rel / TR) : -1;

    const char* kvg = (const char*)kv_cache + (size_t)b * S * LORA * 4;
    const char* peg = (const char*)kpe_cache + (size_t)b * S * ROPE * 4;
    const float* kc_b = k_c_normed + (size_t)b * LORA;
    const float* kr_b = kpe_rot + (size_t)b * ROPE;

    const int wo = wave * 1024 + lane * 16;

    auto stage = [&](int bi, int tile) {
        const char* gk = kvg + (size_t)(s0 + tile * TR) * (LORA * 4);
        char* lk = (char*)&lds_kv[bi][0][0];
#pragma unroll
        for (int i = 0; i < 4; ++i) {
            __builtin_amdgcn_global_load_lds(
                (const __attribute__((address_space(1))) void*)(gk + i * 4096 + wo),
                (__attribute__((address_space(3))) void*)(lk + i * 4096 + wave * 1024),
                16, 0, 0);
        }
        if (t < 128) {
            const char* gp = peg + (size_t)(s0 + tile * TR) * (ROPE * 4);
            char* lp = (char*)&lds_pe[bi][0][0];
            __builtin_amdgcn_global_load_lds(
                (const __attribute__((address_space(1))) void*)(gp + wo),
                (__attribute__((address_space(3))) void*)(lp + wave * 1024),
                16, 0, 0);
        }
    };
    auto patch = [&](int bi, int prow) {
        if (t < 128)
            ((float4*)&lds_kv[bi][prow][0])[t] = ((const float4*)kc_b)[t];
        else if (t < 144)
            ((float4*)&lds_pe[bi][prow][0])[t - 128] = ((const float4*)kr_b)[t - 128];
    };

    float4 q4[9];
    const float* qn = q_nope + ((size_t)b * H + g) * LORA;
#pragma unroll
    for (int k = 0; k < 8; k++) q4[k] = *(const float4*)(qn + 4 * j + 64 * k);
    q4[8] = *(const float4*)(q_pe + ((size_t)b * H + g) * 64 + 4 * j);

    float m_run = -INFINITY, l_run = 0.f;
    float4 o_acc[8];
#pragma unroll
    for (int k = 0; k < 8; k++) o_acc[k] = make_float4(0.f, 0.f, 0.f, 0.f);

    // prologue: stage tile 0
    stage(0, 0);
    asm volatile("s_waitcnt vmcnt(0)" ::: "memory");
    __syncthreads();
    if (ptile == 0) { patch(0, rel); __syncthreads(); }

    int cur = 0;
    for (int tile = 0; tile < NT; ++tile) {
        if (tile + 1 < NT) stage(cur ^ 1, tile + 1); // async, in flight during compute

        for (int r = 0; r < TR; ++r) {
            const float* kvr = &lds_kv[cur][r][0];
            float4 kv4[8];
#pragma unroll
            for (int k = 0; k < 8; k++) kv4[k] = *(const float4*)(kvr + 4 * j + 64 * k);
            float4 p4 = *(const float4*)(&lds_pe[cur][r][0] + 4 * j);

            float acc = 0.f;
#pragma unroll
            for (int k = 0; k < 8; k++)
                acc += q4[k].x * kv4[k].x + q4[k].y * kv4[k].y +
                       q4[k].z * kv4[k].z + q4[k].w * kv4[k].w;
            acc += q4[8].x * p4.x + q4[8].y * p4.y + q4[8].z * p4.z + q4[8].w * p4.w;
            acc += __shfl_xor(acc, 8);
            acc += __shfl_xor(acc, 4);
            acc += __shfl_xor(acc, 2);
            acc += __shfl_xor(acc, 1);
            const float sc = acc * SCALE_C;

            if (sc > m_run + 8.0f) { // defer-max rescale (exp(-inf)=0 on first hit)
                const float alpha = __expf(m_run - sc);
                l_run *= alpha;
#pragma unroll
                for (int k = 0; k < 8; k++) {
                    o_acc[k].x *= alpha; o_acc[k].y *= alpha;
                    o_acc[k].z *= alpha; o_acc[k].w *= alpha;
                }
                m_run = sc;
            }
            const float p = __expf(sc - m_run); // bounded by e^8
            l_run += p;
#pragma unroll
            for (int k = 0; k < 8; k++) {
                o_acc[k].x += p * kv4[k].x; o_acc[k].y += p * kv4[k].y;
                o_acc[k].z += p * kv4[k].z; o_acc[k].w += p * kv4[k].w;
            }
        }

        asm volatile("s_waitcnt vmcnt(0)" ::: "memory");
        __syncthreads();
        if (tile + 1 < NT && ptile == tile + 1) {
            patch(cur ^ 1, rel - ptile * TR);
            __syncthreads();
        }
        cur ^= 1;
    }

    float* po = part_o + (((size_t)b * NC + c) * H + g) * LORA;
#pragma unroll
    for (int k = 0; k < 8; k++) *(float4*)(po + 4 * j + 64 * k) = o_acc[k];
    if (j == 0) {
        float* pml = part_ml + (((size_t)b * NC + c) * H + g) * 2;
        pml[0] = m_run;
        pml[1] = l_run;
    }
}

// ---------------- Kernel 5: combine partials -> o (in LDS), fused v = o . W_UV
__global__ void k_combine(const float* __restrict__ part_o, const float* __restrict__ part_ml,
                          const float* __restrict__ W_UV, float* __restrict__ v) {
    const int h = blockIdx.x, b = blockIdx.y, t = threadIdx.x; // 128 threads
    __shared__ float o_s[LORA];
    float m = -INFINITY;
    for (int c = 0; c < NC; c++)
        m = fmaxf(m, part_ml[(((size_t)b * NC + c) * H + h) * 2]);
    float l = 0.f;
    for (int c = 0; c < NC; c++) {
        const float* pml = part_ml + (((size_t)b * NC + c) * H + h) * 2;
        l += pml[1] * __expf(pml[0] - m);
    }
    const float inv_l = 1.0f / l;
    for (int li = t; li < LORA; li += 128) {
        float acc = 0.f;
        for (int c = 0; c < NC; c++) {
            const float scf = __expf(part_ml[(((size_t)b * NC + c) * H + h) * 2] - m);
            acc += part_o[(((size_t)b * NC + c) * H + h) * LORA + li] * scf;
        }
        o_s[li] = acc * inv_l;
    }
    __syncthreads();
    // v[b, h*128 + t] = sum_l o_s[l] * W_UV[l, h, t]
    float acc = 0.f;
    for (int l2 = 0; l2 < LORA; l2++)
        acc += o_s[l2] * W_UV[(size_t)l2 * (H * VH) + h * VH + t];
    v[(size_t)b * (H * VH) + h * VH + t] = acc;
}

// ---------------- Kernel 6: out_part[ks] = V[:, k-slice] @ W_O[k-slice, :]
__global__ void k_out(const float* __restrict__ v, const float* __restrict__ W_O,
                      float* __restrict__ out_part) {
    const int dsl = blockIdx.x, ksl = blockIdx.y, t = threadIdx.x;
    const int d0 = dsl * 128, k0 = ksl * 128;
    __shared__ float vs[32][128];
    for (int i = t; i < 32 * 128; i += 256) {
        const int bi = i >> 7, kk = i & 127;
        vs[bi][kk] = v[(size_t)bi * DM + k0 + kk];
    }
    __syncthreads();
    const int dl = t & 127, bh = t >> 7; // bh = 0/1 -> batches 0..15 / 16..31
    float acc[16];
#pragma unroll
    for (int i = 0; i < 16; i++) acc[i] = 0.f;
    for (int kk = 0; kk < 128; kk++) {
        const float w = W_O[(size_t)(k0 + kk) * DM + d0 + dl];
#pragma unroll
        for (int i = 0; i < 16; i++) acc[i] += vs[bh * 16 + i][kk] * w;
    }
    float* op = out_part + (size_t)ksl * 32 * DM;
#pragma unroll
    for (int i = 0; i < 16; i++) op[(size_t)(bh * 16 + i) * DM + d0 + dl] = acc[i];
}

// ---------------- Kernel 7: reduce the 16 split-K partials
__global__ void k_out_reduce(const float* __restrict__ out_part, float* __restrict__ out) {
    const int idx = blockIdx.x * 256 + threadIdx.x; // 16384 threads * 4 elems
    float4 acc = make_float4(0.f, 0.f, 0.f, 0.f);
    for (int ks = 0; ks < 16; ks++) {
        float4 p = *(const float4*)(out_part + (size_t)ks * (32 * DM) + (size_t)idx * 4);
        acc.x += p.x; acc.y += p.y; acc.z += p.z; acc.w += p.w;
    }
    *(float4*)(out + (size_t)idx * 4) = acc;
}

extern "C" void kernel_launch(void* const* d_in, const int* in_sizes, int n_in,
                              void* d_out, int out_size, void* d_ws, size_t ws_size,
                              hipStream_t stream) {
    const float* q_c        = (const float*)d_in[0];
    const float* k_c_normed = (const float*)d_in[1];
    const float* k_pe       = (const float*)d_in[2];
    const float* kv_c_cache = (const float*)d_in[3];
    const float* k_pe_cache = (const float*)d_in[4];
    const float* W_UQ       = (const float*)d_in[5];
    const float* W_UK       = (const float*)d_in[6];
    const float* W_QR       = (const float*)d_in[7];
    const float* W_UV       = (const float*)d_in[8];
    const float* W_O        = (const float*)d_in[9];
    const int*   pos        = (const int*)d_in[10];

    float* ws = (float*)d_ws;
    float* q_t      = ws;                       // 65536
    float* qr       = q_t + 65536;              // 32768
    float* q_pe     = qr + 32768;               // 32768
    float* kpe_rot  = q_pe + 32768;             // 2048
    float* q_nope   = kpe_rot + 2048;           // 262144
    float* part_o   = q_nope + 262144;          // 32*NC*16*512 = 8388608
    float* part_ml  = part_o + (size_t)B * NC * H * LORA;   // 32768
    float* v        = part_ml + (size_t)B * NC * H * 2;     // 65536
    float* out_part = v + 65536;                // 16*32*2048 = 1048576

    k_proj1<<<dim3(12, 32), 256, 0, stream>>>(q_c, W_UQ, W_QR, q_t, qr);
    k_rope<<<32, 256, 0, stream>>>(qr, k_pe, pos, q_pe, kpe_rot);
    k_qnope<<<dim3(16, 32), 256, 0, stream>>>(q_t, W_UK, q_nope);
    k_flash<<<B * NC, 256, 0, stream>>>(q_nope, q_pe, kv_c_cache, k_pe_cache,
                                        k_c_normed, kpe_rot, pos, part_o, part_ml);
    k_combine<<<dim3(16, 32), 128, 0, stream>>>(part_o, part_ml, W_UV, v);
    k_out<<<dim3(16, 16), 256, 0, stream>>>(v, W_O, out_part);
    k_out_reduce<<<64, 256, 0, stream>>>(out_part, (float*)d_out);
}

// Round 5
// 231.003 us; speedup vs baseline: 5.5470x; 1.3693x over previous
//
#include <hip/hip_runtime.h>
#include <hip/hip_bf16.h>
#include <math.h>

#define B 32
#define S 4096
#define H 16
#define QC 1536
#define LORA 512
#define ROPE 64
#define NOPE 128
#define VH 128
#define DM 2048
#define NC 32          // chunks per batch for flash split-K
#define CHUNK (S / NC) // 128 rows per chunk
#define TR 8           // rows per staged LDS tile
#define NT (CHUNK / TR)
#define NKS 24         // k-slices for proj1 split-K (1536/64)

__device__ __constant__ float SCALE_C = 0.07216878364870323f; // 1/sqrt(192)

// ---------------- Kernel 1a: proj partials. grid (NKS=24, 12 col-slices), 256 thr.
// cols 0..2047 -> W_UQ, 2048..3071 -> W_QR. Each W element read exactly once.
__global__ __launch_bounds__(256) void k_proj_part(
    const float* __restrict__ q_c, const float* __restrict__ W_UQ,
    const float* __restrict__ W_QR, float* __restrict__ part) {
    const int ks = blockIdx.x, cs = blockIdx.y, t = threadIdx.x;
    const int k0 = ks * 64;
    __shared__ float qs[64][32]; // [k][b]
    for (int i = t; i < 64 * 32; i += 256) {
        const int k = i >> 5, b2 = i & 31;
        qs[k][b2] = q_c[(size_t)b2 * QC + k0 + k];
    }
    __syncthreads();
    const int tc = t & 63, tb = t >> 6; // 4 cols per tc, 8 batches per tb(=wave)
    const int col = cs * 256 + tc * 4;
    const float* W; int N, coll;
    if (cs < 8) { W = W_UQ; N = 2048; coll = col; }
    else        { W = W_QR; N = 1024; coll = col - 2048; }
    float4 acc[8];
#pragma unroll
    for (int i = 0; i < 8; i++) acc[i] = make_float4(0.f, 0.f, 0.f, 0.f);
#pragma unroll 4
    for (int k = 0; k < 64; ++k) {
        const float4 w4 = *(const float4*)(W + (size_t)(k0 + k) * N + coll);
        const float4 a1 = *(const float4*)&qs[k][tb * 8];
        const float4 a2 = *(const float4*)&qs[k][tb * 8 + 4];
        acc[0].x += a1.x * w4.x; acc[0].y += a1.x * w4.y; acc[0].z += a1.x * w4.z; acc[0].w += a1.x * w4.w;
        acc[1].x += a1.y * w4.x; acc[1].y += a1.y * w4.y; acc[1].z += a1.y * w4.z; acc[1].w += a1.y * w4.w;
        acc[2].x += a1.z * w4.x; acc[2].y += a1.z * w4.y; acc[2].z += a1.z * w4.z; acc[2].w += a1.z * w4.w;
        acc[3].x += a1.w * w4.x; acc[3].y += a1.w * w4.y; acc[3].z += a1.w * w4.z; acc[3].w += a1.w * w4.w;
        acc[4].x += a2.x * w4.x; acc[4].y += a2.x * w4.y; acc[4].z += a2.x * w4.z; acc[4].w += a2.x * w4.w;
        acc[5].x += a2.y * w4.x; acc[5].y += a2.y * w4.y; acc[5].z += a2.y * w4.z; acc[5].w += a2.y * w4.w;
        acc[6].x += a2.z * w4.x; acc[6].y += a2.z * w4.y; acc[6].z += a2.z * w4.z; acc[6].w += a2.z * w4.w;
        acc[7].x += a2.w * w4.x; acc[7].y += a2.w * w4.y; acc[7].z += a2.w * w4.z; acc[7].w += a2.w * w4.w;
    }
#pragma unroll
    for (int j = 0; j < 8; j++) {
        const int b2 = tb * 8 + j;
        *(float4*)(part + ((size_t)ks * 32 + b2) * 3072 + col) = acc[j];
    }
}

// ---------------- Kernel 1b: reduce 24 partials -> q_t (32x2048), qr (32x1024)
__global__ void k_proj_reduce(const float* __restrict__ part, float* __restrict__ q_t,
                              float* __restrict__ qr) {
    const int idx = blockIdx.x * 256 + threadIdx.x; // 24576 float4s
    const int b = idx / 768, c4 = idx % 768;
    const int col = c4 * 4;
    float4 acc = make_float4(0.f, 0.f, 0.f, 0.f);
    for (int ks = 0; ks < NKS; ks++) {
        const float4 p = *(const float4*)(part + ((size_t)ks * 32 + b) * 3072 + col);
        acc.x += p.x; acc.y += p.y; acc.z += p.z; acc.w += p.w;
    }
    if (col < 2048) *(float4*)(q_t + (size_t)b * 2048 + col) = acc;
    else            *(float4*)(qr + (size_t)b * 1024 + col - 2048) = acc;
}

// ---------------- Kernel 2: RoPE  (q_pe from qr; kpe_rot from k_pe)
__global__ void k_rope(const float* __restrict__ qr, const float* __restrict__ k_pe,
                       const int* __restrict__ pos_arr, float* __restrict__ q_pe,
                       float* __restrict__ kpe_rot) {
    const int b = blockIdx.x, t = threadIdx.x;
    const int pos = pos_arr[b];
    for (int p = t; p < (H + 1) * 32; p += 256) {
        const int j = p & 31;
        const int grp = p >> 5;
        const double inv = pow(10000.0, -(double)j / 32.0);
        const double f = (double)pos * inv;
        const float c = (float)cos(f), s = (float)sin(f);
        if (grp < H) {
            const float* x = qr + (size_t)b * 1024 + grp * 64;
            float* o = q_pe + (size_t)b * 1024 + grp * 64;
            const float x1 = x[j], x2 = x[j + 32];
            o[j] = x1 * c - x2 * s;
            o[j + 32] = x2 * c + x1 * s;
        } else {
            const float* x = k_pe + (size_t)b * 64;
            float* o = kpe_rot + (size_t)b * 64;
            const float x1 = x[j], x2 = x[j + 32];
            o[j] = x1 * c - x2 * s;
            o[j + 32] = x2 * c + x1 * s;
        }
    }
}

// ---------------- Kernel 3: q_nope[b,h,l] = sum_n q_t[b,h,n] * W_UK[l,h,n]
// grid (8 l-slices, 8 batch-groups, 16 heads); W reads coalesced over n.
__global__ __launch_bounds__(256) void k_qnope(
    const float* __restrict__ q_t, const float* __restrict__ W_UK,
    float* __restrict__ q_nope) {
    const int l0 = blockIdx.x * 64, b0 = blockIdx.y * 4, h = blockIdx.z;
    const int t = threadIdx.x;
    __shared__ float qs[4][NOPE];
    for (int i = t; i < 4 * NOPE; i += 256) {
        const int b2 = i >> 7, n = i & 127;
        qs[b2][n] = q_t[(size_t)(b0 + b2) * 2048 + h * NOPE + n];
    }
    __syncthreads();
    const int wave = t >> 6, lane = t & 63;
    const int half = lane >> 5, nl = (lane & 31) * 4;
    for (int sw = 0; sw < 8; ++sw) {
        const int l = l0 + sw * 8 + wave * 2 + half;
        const float4 w4 = *(const float4*)(W_UK + ((size_t)l * H + h) * NOPE + nl);
#pragma unroll
        for (int b2 = 0; b2 < 4; ++b2) {
            const float4 a4 = *(const float4*)&qs[b2][nl];
            float d = a4.x * w4.x + a4.y * w4.y + a4.z * w4.z + a4.w * w4.w;
            d += __shfl_xor(d, 16);
            d += __shfl_xor(d, 8);
            d += __shfl_xor(d, 4);
            d += __shfl_xor(d, 2);
            d += __shfl_xor(d, 1);
            if ((lane & 31) == 0)
                q_nope[((size_t)(b0 + b2) * H + h) * LORA + l] = d;
        }
    }
}

// ---------------- Kernel 4: flash decode, LDS double-buffered via global_load_lds
__global__ __launch_bounds__(256) void k_flash(
    const float* __restrict__ q_nope, const float* __restrict__ q_pe,
    const float* __restrict__ kv_cache, const float* __restrict__ kpe_cache,
    const float* __restrict__ k_c_normed, const float* __restrict__ kpe_rot,
    const int* __restrict__ pos_arr, float* __restrict__ part_o,
    float* __restrict__ part_ml) {
    __shared__ float lds_kv[2][TR][LORA]; // 32 KB
    __shared__ float lds_pe[2][TR][ROPE]; //  4 KB
    const int blk = blockIdx.x;
    const int b = blk / NC, c = blk % NC;
    const int t = threadIdx.x;
    const int g = t >> 4, j = t & 15;
    const int wave = t >> 6, lane = t & 63;
    const int pos = pos_arr[b];
    const int s0 = c * CHUNK;
    const int rel = pos - s0;
    const int ptile = (rel >= 0 && rel < CHUNK) ? (rel / TR) : -1;

    const char* kvg = (const char*)kv_cache + (size_t)b * S * LORA * 4;
    const char* peg = (const char*)kpe_cache + (size_t)b * S * ROPE * 4;
    const float* kc_b = k_c_normed + (size_t)b * LORA;
    const float* kr_b = kpe_rot + (size_t)b * ROPE;

    const int wo = wave * 1024 + lane * 16;

    auto stage = [&](int bi, int tile) {
        const char* gk = kvg + (size_t)(s0 + tile * TR) * (LORA * 4);
        char* lk = (char*)&lds_kv[bi][0][0];
#pragma unroll
        for (int i = 0; i < 4; ++i) {
            __builtin_amdgcn_global_load_lds(
                (const __attribute__((address_space(1))) void*)(gk + i * 4096 + wo),
                (__attribute__((address_space(3))) void*)(lk + i * 4096 + wave * 1024),
                16, 0, 0);
        }
        if (t < 128) {
            const char* gp = peg + (size_t)(s0 + tile * TR) * (ROPE * 4);
            char* lp = (char*)&lds_pe[bi][0][0];
            __builtin_amdgcn_global_load_lds(
                (const __attribute__((address_space(1))) void*)(gp + wo),
                (__attribute__((address_space(3))) void*)(lp + wave * 1024),
                16, 0, 0);
        }
    };
    auto patch = [&](int bi, int prow) {
        if (t < 128)
            ((float4*)&lds_kv[bi][prow][0])[t] = ((const float4*)kc_b)[t];
        else if (t < 144)
            ((float4*)&lds_pe[bi][prow][0])[t - 128] = ((const float4*)kr_b)[t - 128];
    };

    float4 q4[9];
    const float* qn = q_nope + ((size_t)b * H + g) * LORA;
#pragma unroll
    for (int k = 0; k < 8; k++) q4[k] = *(const float4*)(qn + 4 * j + 64 * k);
    q4[8] = *(const float4*)(q_pe + ((size_t)b * H + g) * 64 + 4 * j);

    float m_run = -INFINITY, l_run = 0.f;
    float4 o_acc[8];
#pragma unroll
    for (int k = 0; k < 8; k++) o_acc[k] = make_float4(0.f, 0.f, 0.f, 0.f);

    stage(0, 0);
    asm volatile("s_waitcnt vmcnt(0)" ::: "memory");
    __syncthreads();
    if (ptile == 0) { patch(0, rel); __syncthreads(); }

    int cur = 0;
    for (int tile = 0; tile < NT; ++tile) {
        if (tile + 1 < NT) stage(cur ^ 1, tile + 1);

        for (int r = 0; r < TR; ++r) {
            const float* kvr = &lds_kv[cur][r][0];
            float4 kv4[8];
#pragma unroll
            for (int k = 0; k < 8; k++) kv4[k] = *(const float4*)(kvr + 4 * j + 64 * k);
            float4 p4 = *(const float4*)(&lds_pe[cur][r][0] + 4 * j);

            float acc = 0.f;
#pragma unroll
            for (int k = 0; k < 8; k++)
                acc += q4[k].x * kv4[k].x + q4[k].y * kv4[k].y +
                       q4[k].z * kv4[k].z + q4[k].w * kv4[k].w;
            acc += q4[8].x * p4.x + q4[8].y * p4.y + q4[8].z * p4.z + q4[8].w * p4.w;
            acc += __shfl_xor(acc, 8);
            acc += __shfl_xor(acc, 4);
            acc += __shfl_xor(acc, 2);
            acc += __shfl_xor(acc, 1);
            const float sc = acc * SCALE_C;

            if (sc > m_run + 8.0f) {
                const float alpha = __expf(m_run - sc);
                l_run *= alpha;
#pragma unroll
                for (int k = 0; k < 8; k++) {
                    o_acc[k].x *= alpha; o_acc[k].y *= alpha;
                    o_acc[k].z *= alpha; o_acc[k].w *= alpha;
                }
                m_run = sc;
            }
            const float p = __expf(sc - m_run);
            l_run += p;
#pragma unroll
            for (int k = 0; k < 8; k++) {
                o_acc[k].x += p * kv4[k].x; o_acc[k].y += p * kv4[k].y;
                o_acc[k].z += p * kv4[k].z; o_acc[k].w += p * kv4[k].w;
            }
        }

        asm volatile("s_waitcnt vmcnt(0)" ::: "memory");
        __syncthreads();
        if (tile + 1 < NT && ptile == tile + 1) {
            patch(cur ^ 1, rel - ptile * TR);
            __syncthreads();
        }
        cur ^= 1;
    }

    float* po = part_o + (((size_t)b * NC + c) * H + g) * LORA;
#pragma unroll
    for (int k = 0; k < 8; k++) *(float4*)(po + 4 * j + 64 * k) = o_acc[k];
    if (j == 0) {
        float* pml = part_ml + (((size_t)b * NC + c) * H + g) * 2;
        pml[0] = m_run;
        pml[1] = l_run;
    }
}

// ---------------- Kernel 5: combine partials -> o (LDS), fused v = o . W_UV
// grid (8 batch-groups, 16 heads), 256 threads.
__global__ __launch_bounds__(256) void k_combine(
    const float* __restrict__ part_o, const float* __restrict__ part_ml,
    const float* __restrict__ W_UV, float* __restrict__ v) {
    const int b0 = blockIdx.x * 4, h = blockIdx.y, t = threadIdx.x;
    __shared__ float ml_s[4][NC][2];
    __shared__ float o_s[4][LORA]; // 8 KB
    if (t < 256) {
        const int b2 = t >> 6, c = (t >> 1) & 31, w = t & 1;
        ml_s[b2][c][w] = part_ml[(((size_t)(b0 + b2) * NC + c) * H + h) * 2 + w];
    }
    __syncthreads();
    float m_b[4], inv_l[4];
#pragma unroll
    for (int b2 = 0; b2 < 4; ++b2) {
        float m = -INFINITY;
        for (int c = 0; c < NC; c++) m = fmaxf(m, ml_s[b2][c][0]);
        float l = 0.f;
        for (int c = 0; c < NC; c++) l += ml_s[b2][c][1] * __expf(ml_s[b2][c][0] - m);
        m_b[b2] = m;
        inv_l[b2] = 1.0f / l;
    }
    for (int i = t; i < 4 * LORA; i += 256) {
        const int b2 = i >> 9, li = i & 511;
        float acc = 0.f;
        for (int c = 0; c < NC; c++) {
            acc += part_o[(((size_t)(b0 + b2) * NC + c) * H + h) * LORA + li] *
                   __expf(ml_s[b2][c][0] - m_b[b2]);
        }
        o_s[b2][li] = acc * inv_l[b2];
    }
    __syncthreads();
    const int vi = t & 127, bp = t >> 7; // bp: 2 batch-pairs
    float acc0 = 0.f, acc1 = 0.f;
    for (int l = 0; l < LORA; l += 4) {
        const float w0 = W_UV[(size_t)(l + 0) * (H * VH) + h * VH + vi];
        const float w1 = W_UV[(size_t)(l + 1) * (H * VH) + h * VH + vi];
        const float w2 = W_UV[(size_t)(l + 2) * (H * VH) + h * VH + vi];
        const float w3 = W_UV[(size_t)(l + 3) * (H * VH) + h * VH + vi];
        const float4 oa = *(const float4*)&o_s[bp * 2][l];
        const float4 ob = *(const float4*)&o_s[bp * 2 + 1][l];
        acc0 += oa.x * w0 + oa.y * w1 + oa.z * w2 + oa.w * w3;
        acc1 += ob.x * w0 + ob.y * w1 + ob.z * w2 + ob.w * w3;
    }
    v[(size_t)(b0 + bp * 2) * (H * VH) + h * VH + vi] = acc0;
    v[(size_t)(b0 + bp * 2 + 1) * (H * VH) + h * VH + vi] = acc1;
}

// ---------------- Kernel 6: out_part[ks] = V[:, k-slice] @ W_O[k-slice, :]
__global__ void k_out(const float* __restrict__ v, const float* __restrict__ W_O,
                      float* __restrict__ out_part) {
    const int dsl = blockIdx.x, ksl = blockIdx.y, t = threadIdx.x;
    const int d0 = dsl * 128, k0 = ksl * 128;
    __shared__ float vs[32][128];
    for (int i = t; i < 32 * 128; i += 256) {
        const int bi = i >> 7, kk = i & 127;
        vs[bi][kk] = v[(size_t)bi * DM + k0 + kk];
    }
    __syncthreads();
    const int dl = t & 127, bh = t >> 7;
    float acc[16];
#pragma unroll
    for (int i = 0; i < 16; i++) acc[i] = 0.f;
    for (int kk = 0; kk < 128; kk += 4) {
        const float w0 = W_O[(size_t)(k0 + kk + 0) * DM + d0 + dl];
        const float w1 = W_O[(size_t)(k0 + kk + 1) * DM + d0 + dl];
        const float w2 = W_O[(size_t)(k0 + kk + 2) * DM + d0 + dl];
        const float w3 = W_O[(size_t)(k0 + kk + 3) * DM + d0 + dl];
#pragma unroll
        for (int i = 0; i < 16; i++) {
            const float4 vv = *(const float4*)&vs[bh * 16 + i][kk];
            acc[i] += vv.x * w0 + vv.y * w1 + vv.z * w2 + vv.w * w3;
        }
    }
    float* op = out_part + (size_t)ksl * 32 * DM;
#pragma unroll
    for (int i = 0; i < 16; i++) op[(size_t)(bh * 16 + i) * DM + d0 + dl] = acc[i];
}

// ---------------- Kernel 7: reduce the 16 split-K partials
__global__ void k_out_reduce(const float* __restrict__ out_part, float* __restrict__ out) {
    const int idx = blockIdx.x * 256 + threadIdx.x;
    float4 acc = make_float4(0.f, 0.f, 0.f, 0.f);
    for (int ks = 0; ks < 16; ks++) {
        float4 p = *(const float4*)(out_part + (size_t)ks * (32 * DM) + (size_t)idx * 4);
        acc.x += p.x; acc.y += p.y; acc.z += p.z; acc.w += p.w;
    }
    *(float4*)(out + (size_t)idx * 4) = acc;
}

extern "C" void kernel_launch(void* const* d_in, const int* in_sizes, int n_in,
                              void* d_out, int out_size, void* d_ws, size_t ws_size,
                              hipStream_t stream) {
    const float* q_c        = (const float*)d_in[0];
    const float* k_c_normed = (const float*)d_in[1];
    const float* k_pe       = (const float*)d_in[2];
    const float* kv_c_cache = (const float*)d_in[3];
    const float* k_pe_cache = (const float*)d_in[4];
    const float* W_UQ       = (const float*)d_in[5];
    const float* W_UK       = (const float*)d_in[6];
    const float* W_QR       = (const float*)d_in[7];
    const float* W_UV       = (const float*)d_in[8];
    const float* W_O        = (const float*)d_in[9];
    const int*   pos        = (const int*)d_in[10];

    float* ws = (float*)d_ws;
    float* q_t      = ws;                       // 65536
    float* qr       = q_t + 65536;              // 32768
    float* q_pe     = qr + 32768;               // 32768
    float* kpe_rot  = q_pe + 32768;             // 2048
    float* q_nope   = kpe_rot + 2048;           // 262144
    float* part_o   = q_nope + 262144;          // 8388608
    float* part_ml  = part_o + (size_t)B * NC * H * LORA;   // 32768
    float* v        = part_ml + (size_t)B * NC * H * 2;     // 65536
    float* out_part = v + 65536;                // 1048576
    float* proj_part = out_part + (size_t)16 * 32 * DM;     // 24*32*3072 = 2359296

    k_proj_part<<<dim3(NKS, 12), 256, 0, stream>>>(q_c, W_UQ, W_QR, proj_part);
    k_proj_reduce<<<96, 256, 0, stream>>>(proj_part, q_t, qr);
    k_rope<<<32, 256, 0, stream>>>(qr, k_pe, pos, q_pe, kpe_rot);
    k_qnope<<<dim3(8, 8, 16), 256, 0, stream>>>(q_t, W_UK, q_nope);
    k_flash<<<B * NC, 256, 0, stream>>>(q_nope, q_pe, kv_c_cache, k_pe_cache,
                                        k_c_normed, kpe_rot, pos, part_o, part_ml);
    k_combine<<<dim3(8, 16), 256, 0, stream>>>(part_o, part_ml, W_UV, v);
    k_out<<<dim3(16, 16), 256, 0, stream>>>(v, W_O, out_part);
    k_out_reduce<<<64, 256, 0, stream>>>(out_part, (float*)d_out);
}